// Round 3
// baseline (787.221 us; speedup 1.0000x reference)
//
#include <hip/hip_runtime.h>
#include <stdint.h>

#define NROWS   1024
#define NV      100000
#define NSEL    101            // K+1
#define NEED    101            // threshold slack: 100 + possibly-unmasked target
#define POOLW   480            // per-wave pool entries
#define NWAVE   8
#define NTHR    512
#define STRIPE  12500          // NV / NWAVE
#define FULLIT  48             // 48*256 = 12288; tail = 212 = 53 lanes * 4

// JAX threefry2x32, partitionable path: bits(n) = o0 ^ o1 of
// threefry2x32(key=(0,42), counts=(hi=0, lo=n)). Bit-exact (absmax 0.0 R0-R2).
// Hand-written asm: EXACTLY 70 VALU ops (add/alignbit/xor; round 1 folded via
// x0=0, the zero key-injection skipped). rotl(x,r) == v_alignbit_b32 x,x,32-r.
// Rationale: R0-R2 counters imply ~219 executed VALU/elem vs ~80 necessary;
// threefry is the only body big enough to hide that bloat — pin its count.
__device__ __forceinline__ uint32_t jax_random_bits(uint32_t n) {
  uint32_t x0, x1;
#define TFR(sh) "v_add_u32 %0, %0, %1\n\t" \
                "v_alignbit_b32 %1, %1, %1, " #sh "\n\t" \
                "v_xor_b32 %1, %1, %0\n\t"
  asm(// init + round 1 (r=13) folded: x0 = n+42; x1 = rotl(x0,13) ^ x0
      "v_add_u32 %0, 42, %2\n\t"
      "v_alignbit_b32 %1, %0, %0, 19\n\t"
      "v_xor_b32 %1, %1, %0\n\t"
      // rounds 2-4: r = 15,26,6  -> rotr 17,6,26
      TFR(17) TFR(6) TFR(26)
      // inject: x0 += 42; x1 += 0x1BD11BF0 + 1
      "v_add_u32 %0, 42, %0\n\t"
      "v_add_u32 %1, 0x1bd11bf1, %1\n\t"
      // rounds 5-8: r = 17,29,16,24 -> rotr 15,3,16,8
      TFR(15) TFR(3) TFR(16) TFR(8)
      // inject: x0 += 0x1BD11BF0; x1 += 2
      "v_add_u32 %0, 0x1bd11bf0, %0\n\t"
      "v_add_u32 %1, 2, %1\n\t"
      // rounds 9-12: r = 13,15,26,6 -> rotr 19,17,6,26
      TFR(19) TFR(17) TFR(6) TFR(26)
      // inject: x0 += 0 (skipped); x1 += 42 + 3
      "v_add_u32 %1, 45, %1\n\t"
      // rounds 13-16: r = 17,29,16,24 -> rotr 15,3,16,8
      TFR(15) TFR(3) TFR(16) TFR(8)
      // inject: x0 += 42; x1 += 0x1BD11BF0 + 4
      "v_add_u32 %0, 42, %0\n\t"
      "v_add_u32 %1, 0x1bd11bf4, %1\n\t"
      // rounds 17-20: r = 13,15,26,6 -> rotr 19,17,6,26
      TFR(19) TFR(17) TFR(6) TFR(26)
      // inject: x0 += 0x1BD11BF0; x1 += 5; out = x0 ^ x1
      "v_add_u32 %0, 0x1bd11bf0, %0\n\t"
      "v_add_u32 %1, 5, %1\n\t"
      "v_xor_b32 %0, %0, %1"
      : "=&v"(x0), "=&v"(x1)
      : "v"(n));
#undef TFR
  return x0;
}

__device__ __forceinline__ float blk_reduce(float x, int tid, float* wred, bool is_max) {
  #pragma unroll
  for (int off = 32; off >= 1; off >>= 1) {
    float o = __shfl_down(x, off);
    x = is_max ? fmaxf(x, o) : (x + o);
  }
  if ((tid & 63) == 0) wred[tid >> 6] = x;
  __syncthreads();
  float r = wred[0];
  #pragma unroll
  for (int w = 1; w < NTHR / 64; ++w)
    r = is_max ? fmaxf(r, wred[w]) : (r + wred[w]);
  __syncthreads();
  return r;
}

// bin b lives at phys ((b&31)<<6)|(b>>5): scan reads are stride-64 (2-way, free)
__device__ __forceinline__ uint32_t hist_phys(uint32_t b) {
  return ((b & 31u) << 6) | (b >> 5);
}

// smallest real float f with sortable_key(f) >= (b<<21); pred (val>=f) <=> bin(val)>=b
__device__ __forceinline__ float binlow_float(uint32_t b) {
  uint32_t k = b << 21;
  if (k & 0x80000000u) {
    uint32_t fb = k ^ 0x80000000u;
    return (fb >= 0x7F800000u) ? INFINITY : __uint_as_float(fb);
  } else {
    uint32_t fb = ~k;
    return (fb >= 0xFF800000u) ? -INFINITY : __uint_as_float(fb);
  }
}

// wave-local scan of shared hist: highest bin b with suffix-count >= need, else -1.
// Racy reads are safe: counts only grow, so any read <= true count.
__device__ __forceinline__ int wave_scan_thr(volatile uint32_t* hist, int lane, uint32_t need) {
  uint32_t sum = 0;
  #pragma unroll
  for (int j = 0; j < 32; ++j) sum += hist[(j << 6) | lane];
  uint32_t suf = sum;
  #pragma unroll
  for (int off = 1; off < 64; off <<= 1) {
    uint32_t o = __shfl_down(suf, off);
    if (lane + off < 64) suf += o;
  }
  const uint32_t sufnext = suf - sum;
  int b = -1;
  if (suf >= need && sufnext < need) {
    uint32_t cum = sufnext;
    int j = 31;
    for (;; --j) {
      cum += hist[(j << 6) | lane];
      if (cum >= need || j == 0) break;
    }
    b = lane * 32 + j;
  }
  #pragma unroll
  for (int off = 32; off >= 1; off >>= 1) b = max(b, __shfl_xor(b, off));
  return b;
}

// monotone raise of shared threshold; out-of-order thrf writes are stale-LOW -> safe
__device__ __forceinline__ void raise_thr(int b, int lane, uint32_t* thrkey, volatile float* thrf) {
  if (b < 0) return;
  if (lane == 0) {
    uint32_t old = atomicMax(thrkey, (uint32_t)b);
    if ((uint32_t)b > old) *thrf = binlow_float((uint32_t)b);
  }
}

// one element: threefry + clz-prefilter; full gumbel only if any lane might pass.
// Bound: g = -ln(-ln u) <= -ln(1-u) <= (clz(2^23 - u23) - 8)*ln2  (since -ln u >= 1-u).
__device__ __forceinline__ void proc_elem(
    float logit, uint32_t n, uint32_t col, float thrf, float thr_s, int lane,
    float* pv_w, uint32_t* pi_w, uint32_t* hist, uint32_t& cnt) {
  const uint32_t bits = jax_random_bits(n);
  const uint32_t b23 = bits >> 9;
  const uint32_t m = 0x800000u - b23;                 // in [1, 2^23]
  const float clzf = (float)__clz((int)(m | 1u));     // |1: provably nonzero, kills clz(0) guard
  // skip if clz < (thrf - logit)/ln2 + 8;  thr_s = thrf/ln2 + 8 (wave-uniform)
  const float req = fmaf(logit, -1.4426950408889634f, thr_s);
  const bool maybe = (clzf >= req);                   // NaN logit => false
  if (__ballot(maybe) == 0ull) return;
  float f1 = __uint_as_float(b23 | 0x3f800000u) - 1.0f;
  float u = fmaxf(f1, 1.1754943508222875e-38f);
  const float g = -__logf(-__logf(u));                // exact R1 gumbel
  const float val = logit + g;
  const bool pred = maybe && (val >= thrf);
  const unsigned long long mk = __ballot(pred);
  if (mk == 0ull) return;
  const uint32_t pos = cnt + (uint32_t)__popcll(mk & ((1ull << lane) - 1ull));
  if (pred && pos < (uint32_t)POOLW) {
    pv_w[pos] = val;
    pi_w[pos] = col;
    uint32_t fb = __float_as_uint(val);
    uint32_t key = fb ^ (uint32_t)(((int32_t)fb >> 31) | (int32_t)0x80000000);
    atomicAdd(&hist[hist_phys(key >> 21)], 1u);       // hist counts stored elems only
  }
  cnt += (uint32_t)__popcll(mk);
}

__global__ void __launch_bounds__(NTHR, 8)
nce_row_kernel(const float* __restrict__ noise, const float* __restrict__ actual,
               const int* __restrict__ target, float* __restrict__ acc,
               uint32_t* __restrict__ ticket, float* __restrict__ out) {
  const int row = blockIdx.x;
  const int tid = threadIdx.x;
  const int lane = tid & 63;
  const uint32_t w = (uint32_t)tid >> 6;

  __shared__ float    pv[NWAVE * POOLW];
  __shared__ uint32_t pi_[NWAVE * POOLW];
  __shared__ uint32_t uni[2048];        // hist during stream; mv/mi at merge
  __shared__ uint32_t s_cnt[NWAVE];
  __shared__ uint32_t s_thrkey;
  __shared__ float    s_thrf;
  __shared__ float    s_thrf_final;
  __shared__ uint32_t s_mcnt;
  __shared__ float    s_wred[NTHR / 64];

  uint32_t* hist = uni;
  float*    mv   = (float*)uni;         // [0..1023]   (reused after final scan)
  uint32_t* mi   = uni + 1024;          // [0..1023]

  for (int i = tid; i < 2048; i += NTHR) hist[i] = 0u;
  if (tid == 0) { s_thrkey = 0u; s_thrf = -INFINITY; s_mcnt = 0u; }
  __syncthreads();

  const float* rowp = noise + (size_t)row * NV;
  const uint32_t tgt = (uint32_t)target[row];
  const uint32_t nbase = (uint32_t)row * (uint32_t)NV;
  const uint32_t stripe0 = w * (uint32_t)STRIPE;
  const float* sp = rowp + stripe0;
  float*    pv_w = pv  + w * POOLW;
  uint32_t* pi_w = pi_ + w * POOLW;
  volatile float* vthrf = &s_thrf;

  uint32_t cnt = 0;
  const float qnan = __int_as_float(0x7fc00000);

  float4 a = *reinterpret_cast<const float4*>(sp + lane * 4);

  for (int it = 0; it < FULLIT; ++it) {
    float4 an;
    if (it < FULLIT - 1) {
      an = *reinterpret_cast<const float4*>(sp + (it + 1) * 256 + lane * 4);
    } else if (lane < 53) {
      an = *reinterpret_cast<const float4*>(sp + FULLIT * 256 + lane * 4);
    }

    const float thrf = *vthrf;                        // monotone, stale-low safe
    const float thr_s = fmaf(thrf, 1.4426950408889634f, 8.0f);
    const uint32_t e0 = stripe0 + (uint32_t)(it * 256 + lane * 4);
    proc_elem(a.x, nbase + e0 + 0u, e0 + 0u, thrf, thr_s, lane, pv_w, pi_w, hist, cnt);
    proc_elem(a.y, nbase + e0 + 1u, e0 + 1u, thrf, thr_s, lane, pv_w, pi_w, hist, cnt);
    proc_elem(a.z, nbase + e0 + 2u, e0 + 2u, thrf, thr_s, lane, pv_w, pi_w, hist, cnt);
    proc_elem(a.w, nbase + e0 + 3u, e0 + 3u, thrf, thr_s, lane, pv_w, pi_w, hist, cnt);

    if (cnt > (uint32_t)(POOLW - 256)) {
      // compact: raise thr from hist, then refilter own pool in place
      int b = wave_scan_thr(hist, lane, NEED);
      raise_thr(b, lane, &s_thrkey, vthrf);
      const float tf = *vthrf;
      const uint32_t n0 = min(cnt, (uint32_t)POOLW);
      uint32_t nc = 0;
      for (uint32_t p0 = 0; p0 < n0; p0 += 64) {
        const uint32_t p = p0 + (uint32_t)lane;
        const bool v = (p < n0);
        float vv = 0.0f; uint32_t ii = 0;
        if (v) { vv = pv_w[p]; ii = pi_w[p]; }
        const bool keep = v && (vv >= tf);
        const unsigned long long km = __ballot(keep);
        const uint32_t np = nc + (uint32_t)__popcll(km & ((1ull << lane) - 1ull));
        if (keep) { pv_w[np] = vv; pi_w[np] = ii; }
        nc += (uint32_t)__popcll(km);
      }
      cnt = nc;
    } else if ((it & 15) == 7) {
      int b = wave_scan_thr(hist, lane, NEED);
      raise_thr(b, lane, &s_thrkey, vthrf);
    }
    a = an;
  }

  { // tail: 212 elements = 53 lanes x 4; invalid lanes get NaN logits (fail prefilter)
    const float thrf = *vthrf;
    const float thr_s = fmaf(thrf, 1.4426950408889634f, 8.0f);
    const uint32_t e0 = stripe0 + (uint32_t)(FULLIT * 256 + lane * 4);
    const bool lv = (lane < 53);
    proc_elem(lv ? a.x : qnan, nbase + e0 + 0u, e0 + 0u, thrf, thr_s, lane, pv_w, pi_w, hist, cnt);
    proc_elem(lv ? a.y : qnan, nbase + e0 + 1u, e0 + 1u, thrf, thr_s, lane, pv_w, pi_w, hist, cnt);
    proc_elem(lv ? a.z : qnan, nbase + e0 + 2u, e0 + 2u, thrf, thr_s, lane, pv_w, pi_w, hist, cnt);
    proc_elem(lv ? a.w : qnan, nbase + e0 + 3u, e0 + 3u, thrf, thr_s, lane, pv_w, pi_w, hist, cnt);
  }

  if (lane == 0) s_cnt[w] = min(cnt, (uint32_t)POOLW);
  __syncthreads();

  // exact final threshold from complete hist (wave 0)
  if (tid < 64) {
    int b = wave_scan_thr(hist, lane, NEED);          // b >= 0 guaranteed (hist >= NEED)
    if (lane == 0) s_thrf_final = binlow_float((uint32_t)(b < 0 ? 0 : b));
  }
  __syncthreads();
  const float tf = s_thrf_final;

  // merge-compact all pools' entries >= tf (excluding target) into mv/mi (aliases hist)
  for (uint32_t s = tid; s < (uint32_t)(NWAVE * POOLW); s += NTHR) {
    const uint32_t wq = s / POOLW;
    const uint32_t p = s - wq * POOLW;
    bool keep = (p < s_cnt[wq]);
    float vv = 0.0f; uint32_t ii = 0;
    if (keep) {
      vv = pv[s]; ii = pi_[s];
      keep = (vv >= tf) && (ii != tgt);
    }
    const unsigned long long km = __ballot(keep);
    const uint32_t nb = (uint32_t)__popcll(km);
    if (nb) {
      uint32_t base = 0;
      if (lane == 0) base = atomicAdd(&s_mcnt, nb);
      base = __shfl(base, 0);
      if (keep) {
        const uint32_t pos = base + (uint32_t)__popcll(km & ((1ull << lane) - 1ull));
        if (pos < 1024u) { mv[pos] = vv; mi[pos] = ii; }
      }
    }
  }
  __syncthreads();
  const uint32_t mc = min(s_mcnt, 1024u);
  for (uint32_t i = mc + tid; i < 1024u; i += NTHR) { mv[i] = -INFINITY; mi[i] = 0xFFFFFFFFu; }
  __syncthreads();

  // bitonic sort 1024 desc by (val, idx asc) — matches lax.top_k tie-breaking
  for (uint32_t ksz = 2; ksz <= 1024u; ksz <<= 1) {
    for (uint32_t jsz = ksz >> 1; jsz >= 1; jsz >>= 1) {
      for (uint32_t i = tid; i < 1024u; i += NTHR) {
        const uint32_t ixj = i ^ jsz;
        if (ixj > i) {
          const bool desc = ((i & ksz) == 0);
          float va = mv[i], vb = mv[ixj];
          uint32_t ia = mi[i], ib = mi[ixj];
          const bool a_less = (va < vb) || (va == vb && ia > ib);
          if (desc ? a_less : !a_less) {
            mv[i] = vb; mv[ixj] = va; mi[i] = ib; mi[ixj] = ia;
          }
        }
      }
      __syncthreads();
    }
  }

  // scoring: softmax over gathered noise logits & actual logits
  float nl = -INFINITY, al = -INFINITY;
  if (tid < NSEL) {
    const uint32_t idx = (tid == 0) ? tgt : mi[tid - 1];
    nl = rowp[idx];                            // original (unmasked) logits
    al = actual[(size_t)row * NSEL + tid];
  }
  const float mn = blk_reduce(nl, tid, s_wred, true);
  const float ma = blk_reduce(al, tid, s_wred, true);
  const float en = (tid < NSEL) ? __expf(nl - mn) : 0.0f;
  const float ea = (tid < NSEL) ? __expf(al - ma) : 0.0f;
  const float sn = blk_reduce(en, tid, s_wred, false);
  const float sa = blk_reduce(ea, tid, s_wred, false);

  float contrib = 0.0f;
  if (tid < NSEL) {
    const float npj = en / sn;
    const float apj = ea / sa;
    const float deno = 100.0f * npj + apj + 1e-6f;
    float t = (tid == 0) ? (apj / deno) : (npj / deno);
    if (t == 1.0f) t = 1.0f + 1e-6f;           // exact reference quirk
    contrib = logf(t);
  }
  const float tot = blk_reduce(contrib, tid, s_wred, false);

  if (tid == 0) {
    atomicAdd(acc, tot);
    __threadfence();
    const uint32_t tk = atomicAdd(ticket, 1u);
    if (tk == (uint32_t)(NROWS - 1)) {
      const float total = atomicAdd(acc, 0.0f);
      out[0] = -total / (1024.0f * 101.0f);
    }
  }
}

extern "C" void kernel_launch(void* const* d_in, const int* in_sizes, int n_in,
                              void* d_out, int out_size, void* d_ws, size_t ws_size,
                              hipStream_t stream) {
  const float* noise  = (const float*)d_in[0];
  const float* actual = (const float*)d_in[1];
  const int*   target = (const int*)d_in[2];
  float* out = (float*)d_out;
  float*    acc    = (float*)d_ws;
  uint32_t* ticket = (uint32_t*)d_ws + 1;

  hipMemsetAsync(d_ws, 0, 8, stream);
  nce_row_kernel<<<NROWS, NTHR, 0, stream>>>(noise, actual, target, acc, ticket, out);
}

// Round 4
// 773.052 us; speedup vs baseline: 1.0183x; 1.0183x over previous
//
#include <hip/hip_runtime.h>
#include <stdint.h>

#define NROWS   1024
#define NV      100000
#define NSEL    101            // K+1
#define NEED    101            // threshold slack: 100 + possibly-unmasked target
#define POOLW   480            // per-wave pool entries
#define NWAVE   8
#define NTHR    512
#define STRIPE  12500          // NV / NWAVE
#define FULLIT  48             // 48*256 = 12288; tail = 212 = 53 lanes * 4

__device__ __forceinline__ uint32_t rotl32(uint32_t x, uint32_t r) {
  return (x << r) | (x >> (32u - r));
}

// JAX threefry2x32, partitionable path: bits(n) = o0 ^ o1 of
// threefry2x32(key=(0,42), counts=(hi=0, lo=n)). Bit-exact (absmax 0.0 R0-R3).
// Compiler codegen kept (R3 proved hand-asm is NOT faster: count was already tight).
__device__ __forceinline__ uint32_t jax_random_bits(uint32_t n) {
  const uint32_t K1 = 42u;
  const uint32_t K2 = 0x1BD11BF0u;
  uint32_t x0 = 0u;
  uint32_t x1 = n + K1;
#define TF_R(r) { x0 += x1; x1 = rotl32(x1, (r)); x1 ^= x0; }
  TF_R(13u) TF_R(15u) TF_R(26u) TF_R(6u)
  x0 += K1; x1 += K2 + 1u;
  TF_R(17u) TF_R(29u) TF_R(16u) TF_R(24u)
  x0 += K2; x1 += 0u + 2u;
  TF_R(13u) TF_R(15u) TF_R(26u) TF_R(6u)
  x0 += 0u; x1 += K1 + 3u;
  TF_R(17u) TF_R(29u) TF_R(16u) TF_R(24u)
  x0 += K1; x1 += K2 + 4u;
  TF_R(13u) TF_R(15u) TF_R(26u) TF_R(6u)
  x0 += K2; x1 += 0u + 5u;
#undef TF_R
  return x0 ^ x1;
}

__device__ __forceinline__ float blk_reduce(float x, int tid, float* wred, bool is_max) {
  #pragma unroll
  for (int off = 32; off >= 1; off >>= 1) {
    float o = __shfl_down(x, off);
    x = is_max ? fmaxf(x, o) : (x + o);
  }
  if ((tid & 63) == 0) wred[tid >> 6] = x;
  __syncthreads();
  float r = wred[0];
  #pragma unroll
  for (int w = 1; w < NTHR / 64; ++w)
    r = is_max ? fmaxf(r, wred[w]) : (r + wred[w]);
  __syncthreads();
  return r;
}

// bin b lives at phys ((b&31)<<6)|(b>>5): scan reads are stride-64 (2-way, free)
__device__ __forceinline__ uint32_t hist_phys(uint32_t b) {
  return ((b & 31u) << 6) | (b >> 5);
}

// smallest real float f with sortable_key(f) >= (b<<21); pred (val>=f) <=> bin(val)>=b
__device__ __forceinline__ float binlow_float(uint32_t b) {
  uint32_t k = b << 21;
  if (k & 0x80000000u) {
    uint32_t fb = k ^ 0x80000000u;
    return (fb >= 0x7F800000u) ? INFINITY : __uint_as_float(fb);
  } else {
    uint32_t fb = ~k;
    return (fb >= 0xFF800000u) ? -INFINITY : __uint_as_float(fb);
  }
}

// wave-local scan of shared hist: highest bin b with suffix-count >= need, else -1.
// Racy reads are safe: counts only grow, so any read <= true count.
__device__ __forceinline__ int wave_scan_thr(volatile uint32_t* hist, int lane, uint32_t need) {
  uint32_t sum = 0;
  #pragma unroll
  for (int j = 0; j < 32; ++j) sum += hist[(j << 6) | lane];
  uint32_t suf = sum;
  #pragma unroll
  for (int off = 1; off < 64; off <<= 1) {
    uint32_t o = __shfl_down(suf, off);
    if (lane + off < 64) suf += o;
  }
  const uint32_t sufnext = suf - sum;
  int b = -1;
  if (suf >= need && sufnext < need) {
    uint32_t cum = sufnext;
    int j = 31;
    for (;; --j) {
      cum += hist[(j << 6) | lane];
      if (cum >= need || j == 0) break;
    }
    b = lane * 32 + j;
  }
  #pragma unroll
  for (int off = 32; off >= 1; off >>= 1) b = max(b, __shfl_xor(b, off));
  return b;
}

// monotone raise of shared threshold; out-of-order thrf writes are stale-LOW -> safe
__device__ __forceinline__ void raise_thr(int b, int lane, uint32_t* thrkey, volatile float* thrf) {
  if (b < 0) return;
  if (lane == 0) {
    uint32_t old = atomicMax(thrkey, (uint32_t)b);
    if ((uint32_t)b > old) *thrf = binlow_float((uint32_t)b);
  }
}

// one element: threefry + clz-prefilter; full gumbel only if any lane might pass.
// Bound: g = -ln(-ln u) <= -ln(1-u) <= (clz(2^23 - u23) - 8)*ln2  (since -ln u >= 1-u).
__device__ __forceinline__ void proc_elem(
    float logit, uint32_t n, uint32_t col, float thrf, float thr_s, int lane,
    float* pv_w, uint32_t* pi_w, uint32_t* hist, uint32_t& cnt) {
  const uint32_t bits = jax_random_bits(n);
  const uint32_t b23 = bits >> 9;
  const uint32_t m = 0x800000u - b23;                 // in [1, 2^23]
  const float clzf = (float)__clz((int)m);
  // skip if clz < (thrf - logit)/ln2 + 8;  thr_s = thrf/ln2 + 8 (wave-uniform)
  const float req = fmaf(logit, -1.4426950408889634f, thr_s);
  const bool maybe = (clzf >= req);                   // NaN logit => false
  if (__ballot(maybe) == 0ull) return;
  float f1 = __uint_as_float(b23 | 0x3f800000u) - 1.0f;
  float u = fmaxf(f1, 1.1754943508222875e-38f);
  const float g = -__logf(-__logf(u));                // exact R1 gumbel
  const float val = logit + g;
  const bool pred = maybe && (val >= thrf);
  const unsigned long long mk = __ballot(pred);
  if (mk == 0ull) return;
  const uint32_t pos = cnt + (uint32_t)__popcll(mk & ((1ull << lane) - 1ull));
  if (pred && pos < (uint32_t)POOLW) {
    pv_w[pos] = val;
    pi_w[pos] = col;
    uint32_t fb = __float_as_uint(val);
    uint32_t key = fb ^ (uint32_t)(((int32_t)fb >> 31) | (int32_t)0x80000000);
    atomicAdd(&hist[hist_phys(key >> 21)], 1u);       // hist counts stored elems only
  }
  cnt += (uint32_t)__popcll(mk);
}

__global__ void __launch_bounds__(NTHR, 8)
nce_row_kernel(const float* __restrict__ noise, const float* __restrict__ actual,
               const int* __restrict__ target, float* __restrict__ acc,
               uint32_t* __restrict__ ticket, float* __restrict__ out) {
  const int row = blockIdx.x;
  const int tid = threadIdx.x;
  const int lane = tid & 63;
  const uint32_t w = (uint32_t)tid >> 6;

  __shared__ float    pv[NWAVE * POOLW];
  __shared__ uint32_t pi_[NWAVE * POOLW];
  __shared__ uint32_t uni[2048];        // hist during stream; mv/mi at merge
  __shared__ uint32_t s_cnt[NWAVE];
  __shared__ uint32_t s_thrkey;
  __shared__ float    s_thrf;
  __shared__ float    s_thrf_final;
  __shared__ uint32_t s_mcnt;
  __shared__ float    s_wred[NTHR / 64];

  uint32_t* hist = uni;
  float*    mv   = (float*)uni;         // [0..1023]   (reused after final scan)
  uint32_t* mi   = uni + 1024;          // [0..1023]

  for (int i = tid; i < 2048; i += NTHR) hist[i] = 0u;
  if (tid == 0) { s_thrkey = 0u; s_thrf = -INFINITY; s_mcnt = 0u; }
  __syncthreads();

  // --- R4: temporal de-phasing of waves (convoy breaker) -----------------
  // All 32 waves/CU otherwise run in lockstep (same code, same per-iteration
  // work, no in-loop barriers) and hit their vmcnt/lgkmcnt waits at the same
  // instant -> whole-SIMD idle bubbles every iteration. One-time skew of
  // ~512 cy/unit spreads wave phases over ~0-8.7K cy; nothing re-syncs them.
  // Timing-only: threshold protocol is safe under arbitrary interleaving.
  {
    const int skew = (int)w * 2 + (int)(blockIdx.x & 3);
    for (int i = 0; i < skew; ++i) __builtin_amdgcn_s_sleep(8);
  }
  // -----------------------------------------------------------------------

  const float* rowp = noise + (size_t)row * NV;
  const uint32_t tgt = (uint32_t)target[row];
  const uint32_t nbase = (uint32_t)row * (uint32_t)NV;
  const uint32_t stripe0 = w * (uint32_t)STRIPE;
  const float* sp = rowp + stripe0;
  float*    pv_w = pv  + w * POOLW;
  uint32_t* pi_w = pi_ + w * POOLW;
  volatile float* vthrf = &s_thrf;

  uint32_t cnt = 0;
  const float qnan = __int_as_float(0x7fc00000);

  float4 a = *reinterpret_cast<const float4*>(sp + lane * 4);

  for (int it = 0; it < FULLIT; ++it) {
    float4 an;
    if (it < FULLIT - 1) {
      an = *reinterpret_cast<const float4*>(sp + (it + 1) * 256 + lane * 4);
    } else if (lane < 53) {
      an = *reinterpret_cast<const float4*>(sp + FULLIT * 256 + lane * 4);
    }

    const float thrf = *vthrf;                        // monotone, stale-low safe
    const float thr_s = fmaf(thrf, 1.4426950408889634f, 8.0f);
    const uint32_t e0 = stripe0 + (uint32_t)(it * 256 + lane * 4);
    proc_elem(a.x, nbase + e0 + 0u, e0 + 0u, thrf, thr_s, lane, pv_w, pi_w, hist, cnt);
    proc_elem(a.y, nbase + e0 + 1u, e0 + 1u, thrf, thr_s, lane, pv_w, pi_w, hist, cnt);
    proc_elem(a.z, nbase + e0 + 2u, e0 + 2u, thrf, thr_s, lane, pv_w, pi_w, hist, cnt);
    proc_elem(a.w, nbase + e0 + 3u, e0 + 3u, thrf, thr_s, lane, pv_w, pi_w, hist, cnt);

    if (cnt > (uint32_t)(POOLW - 256)) {
      // compact: raise thr from hist, then refilter own pool in place
      int b = wave_scan_thr(hist, lane, NEED);
      raise_thr(b, lane, &s_thrkey, vthrf);
      const float tf = *vthrf;
      const uint32_t n0 = min(cnt, (uint32_t)POOLW);
      uint32_t nc = 0;
      for (uint32_t p0 = 0; p0 < n0; p0 += 64) {
        const uint32_t p = p0 + (uint32_t)lane;
        const bool v = (p < n0);
        float vv = 0.0f; uint32_t ii = 0;
        if (v) { vv = pv_w[p]; ii = pi_w[p]; }
        const bool keep = v && (vv >= tf);
        const unsigned long long km = __ballot(keep);
        const uint32_t np = nc + (uint32_t)__popcll(km & ((1ull << lane) - 1ull));
        if (keep) { pv_w[np] = vv; pi_w[np] = ii; }
        nc += (uint32_t)__popcll(km);
      }
      cnt = nc;
    } else if ((it & 15) == 7) {
      int b = wave_scan_thr(hist, lane, NEED);
      raise_thr(b, lane, &s_thrkey, vthrf);
    }
    a = an;
  }

  { // tail: 212 elements = 53 lanes x 4; invalid lanes get NaN logits (fail prefilter)
    const float thrf = *vthrf;
    const float thr_s = fmaf(thrf, 1.4426950408889634f, 8.0f);
    const uint32_t e0 = stripe0 + (uint32_t)(FULLIT * 256 + lane * 4);
    const bool lv = (lane < 53);
    proc_elem(lv ? a.x : qnan, nbase + e0 + 0u, e0 + 0u, thrf, thr_s, lane, pv_w, pi_w, hist, cnt);
    proc_elem(lv ? a.y : qnan, nbase + e0 + 1u, e0 + 1u, thrf, thr_s, lane, pv_w, pi_w, hist, cnt);
    proc_elem(lv ? a.z : qnan, nbase + e0 + 2u, e0 + 2u, thrf, thr_s, lane, pv_w, pi_w, hist, cnt);
    proc_elem(lv ? a.w : qnan, nbase + e0 + 3u, e0 + 3u, thrf, thr_s, lane, pv_w, pi_w, hist, cnt);
  }

  if (lane == 0) s_cnt[w] = min(cnt, (uint32_t)POOLW);
  __syncthreads();

  // exact final threshold from complete hist (wave 0)
  if (tid < 64) {
    int b = wave_scan_thr(hist, lane, NEED);          // b >= 0 guaranteed (hist >= NEED)
    if (lane == 0) s_thrf_final = binlow_float((uint32_t)(b < 0 ? 0 : b));
  }
  __syncthreads();
  const float tf = s_thrf_final;

  // merge-compact all pools' entries >= tf (excluding target) into mv/mi (aliases hist)
  for (uint32_t s = tid; s < (uint32_t)(NWAVE * POOLW); s += NTHR) {
    const uint32_t wq = s / POOLW;
    const uint32_t p = s - wq * POOLW;
    bool keep = (p < s_cnt[wq]);
    float vv = 0.0f; uint32_t ii = 0;
    if (keep) {
      vv = pv[s]; ii = pi_[s];
      keep = (vv >= tf) && (ii != tgt);
    }
    const unsigned long long km = __ballot(keep);
    const uint32_t nb = (uint32_t)__popcll(km);
    if (nb) {
      uint32_t base = 0;
      if (lane == 0) base = atomicAdd(&s_mcnt, nb);
      base = __shfl(base, 0);
      if (keep) {
        const uint32_t pos = base + (uint32_t)__popcll(km & ((1ull << lane) - 1ull));
        if (pos < 1024u) { mv[pos] = vv; mi[pos] = ii; }
      }
    }
  }
  __syncthreads();
  const uint32_t mc = min(s_mcnt, 1024u);
  for (uint32_t i = mc + tid; i < 1024u; i += NTHR) { mv[i] = -INFINITY; mi[i] = 0xFFFFFFFFu; }
  __syncthreads();

  // bitonic sort 1024 desc by (val, idx asc) — matches lax.top_k tie-breaking
  for (uint32_t ksz = 2; ksz <= 1024u; ksz <<= 1) {
    for (uint32_t jsz = ksz >> 1; jsz >= 1; jsz >>= 1) {
      for (uint32_t i = tid; i < 1024u; i += NTHR) {
        const uint32_t ixj = i ^ jsz;
        if (ixj > i) {
          const bool desc = ((i & ksz) == 0);
          float va = mv[i], vb = mv[ixj];
          uint32_t ia = mi[i], ib = mi[ixj];
          const bool a_less = (va < vb) || (va == vb && ia > ib);
          if (desc ? a_less : !a_less) {
            mv[i] = vb; mv[ixj] = va; mi[i] = ib; mi[ixj] = ia;
          }
        }
      }
      __syncthreads();
    }
  }

  // scoring: softmax over gathered noise logits & actual logits
  float nl = -INFINITY, al = -INFINITY;
  if (tid < NSEL) {
    const uint32_t idx = (tid == 0) ? tgt : mi[tid - 1];
    nl = rowp[idx];                            // original (unmasked) logits
    al = actual[(size_t)row * NSEL + tid];
  }
  const float mn = blk_reduce(nl, tid, s_wred, true);
  const float ma = blk_reduce(al, tid, s_wred, true);
  const float en = (tid < NSEL) ? __expf(nl - mn) : 0.0f;
  const float ea = (tid < NSEL) ? __expf(al - ma) : 0.0f;
  const float sn = blk_reduce(en, tid, s_wred, false);
  const float sa = blk_reduce(ea, tid, s_wred, false);

  float contrib = 0.0f;
  if (tid < NSEL) {
    const float npj = en / sn;
    const float apj = ea / sa;
    const float deno = 100.0f * npj + apj + 1e-6f;
    float t = (tid == 0) ? (apj / deno) : (npj / deno);
    if (t == 1.0f) t = 1.0f + 1e-6f;           // exact reference quirk
    contrib = logf(t);
  }
  const float tot = blk_reduce(contrib, tid, s_wred, false);

  if (tid == 0) {
    atomicAdd(acc, tot);
    __threadfence();
    const uint32_t tk = atomicAdd(ticket, 1u);
    if (tk == (uint32_t)(NROWS - 1)) {
      const float total = atomicAdd(acc, 0.0f);
      out[0] = -total / (1024.0f * 101.0f);
    }
  }
}

extern "C" void kernel_launch(void* const* d_in, const int* in_sizes, int n_in,
                              void* d_out, int out_size, void* d_ws, size_t ws_size,
                              hipStream_t stream) {
  const float* noise  = (const float*)d_in[0];
  const float* actual = (const float*)d_in[1];
  const int*   target = (const int*)d_in[2];
  float* out = (float*)d_out;
  float*    acc    = (float*)d_ws;
  uint32_t* ticket = (uint32_t*)d_ws + 1;

  hipMemsetAsync(d_ws, 0, 8, stream);
  nce_row_kernel<<<NROWS, NTHR, 0, stream>>>(noise, actual, target, acc, ticket, out);
}